// Round 5
// baseline (258.993 us; speedup 1.0000x reference)
//
#include <hip/hip_runtime.h>
#include <stdint.h>

typedef unsigned short u16;
typedef unsigned int   u32;
typedef __attribute__((ext_vector_type(8))) short bf16x8;
typedef __attribute__((ext_vector_type(4))) float f32x4;

#define EPS 1e-3f
#define NB 32
#define HW 56
#define CI 256
#define CM 128
#define PIX (NB*HW*HW)   // 100352

__device__ __forceinline__ float asf(u32 i){ union{u32 u; float f;} t; t.u=i; return t.f; }
__device__ __forceinline__ u16 f2bf(float f){
  union{float f; u32 u;} t; t.f = f;
  u32 x = t.u;
  return (u16)((x + 0x7fffu + ((x>>16)&1u)) >> 16);   // RNE
}

// ---------------- prep: MFMA-fragment-swizzled bf16 weights + BN fold ----------------
// w1s: conv1 B-frags [8 t][8 kt][64 lane][8]
// w3s: conv3 B-frags [16 t][4 kc][64 lane][8]
// w2s: conv2 (grouped 3x3) block-diagonal B-frags [8 t][10 pv][64 lane][8]
//      pv 0..4 = hi bf16 of tap-pairs (0,1)(2,3)(4,5)(6,7)(8,pad); pv 5..9 = lo residual.
//      klocal = quad*8+j: <16 -> tapA ci 0..15, >=16 -> tapB ci 0..15.
//      nonzero iff (ci>>2) == (col>>2)  (group-diagonal within the 16-ch slice).
__global__ __launch_bounds__(256) void kprep(
    const float* __restrict__ w1, const float* __restrict__ b1, const float* __restrict__ g1,
    const float* __restrict__ be1, const float* __restrict__ m1, const float* __restrict__ v1,
    const float* __restrict__ w2, const float* __restrict__ b2, const float* __restrict__ g2,
    const float* __restrict__ be2, const float* __restrict__ m2, const float* __restrict__ v2,
    const float* __restrict__ w3,
    u16* __restrict__ w1s, u16* __restrict__ w3s, u16* __restrict__ w2s,
    float* __restrict__ A1, float* __restrict__ B1,
    float* __restrict__ A2, float* __restrict__ B2){
  int i = blockIdx.x*256 + threadIdx.x;
  if (i < 32768){
    { // w1s
      int j = i & 7, lane = (i >> 3) & 63, kt = (i >> 9) & 7, t = i >> 12;
      int col = lane & 15, quad = lane >> 4;
      int n = t*16 + col, k = kt*32 + quad*8 + j;
      w1s[i] = f2bf(w1[k*CM + n]);
    }
    { // w3s
      int j = i & 7, lane = (i >> 3) & 63, kc = (i >> 9) & 3, t = i >> 11;
      int col = lane & 15, quad = lane >> 4;
      int n = t*16 + col, k = kc*32 + quad*8 + j;
      w3s[i] = f2bf(w3[k*CI + n]);
    }
  }
  if (i < 40960){ // w2s
    int j = i & 7, lane = (i >> 3) & 63;
    int pv = (i >> 9) % 10, t = (i >> 9) / 10;
    int pp = pv % 5; bool lo = pv >= 5;
    int col = lane & 15, quad = lane >> 4;
    int klocal = quad*8 + j;
    int tap = (klocal < 16) ? 2*pp : 2*pp + 1;   // tap 9 (pp=4 lo-half of pair) = invalid -> 0
    int c = klocal & 15;
    float wv = 0.f;
    if (tap <= 8 && (c >> 2) == (col >> 2))
      wv = w2[(tap*4 + (c & 3))*CM + t*16 + col];
    u16 hi = f2bf(wv);
    if (!lo) w2s[i] = hi;
    else     w2s[i] = f2bf(wv - asf((u32)hi << 16));
  }
  if (i < 128){
    float s1 = g1[i] * rsqrtf(v1[i] + EPS);
    A1[i] = s1;
    B1[i] = b1[i]*s1 + be1[i] - m1[i]*s1;
    float s2 = g2[i] * rsqrtf(v2[i] + EPS);
    A2[i] = s2;
    B2[i] = b2[i]*s2 + be2[i] - m2[i]*s2;
  }
}

// ---------------- conv1 1x1 256->128 + BN + ReLU (MFMA bf16) ----------------
// round-0 version (best measured): 256 thr, K-chunked LDS, 4 blocks/CU.
#define K1_LS 72   // A-tile row stride (u16)
__global__ __launch_bounds__(256) void k1(const float* __restrict__ x,
    const u16* __restrict__ w1s, const float* __restrict__ A1v,
    const float* __restrict__ B1v, u16* __restrict__ h1){
  __shared__ __align__(16) char smem[128*136*2];
  u16* As = (u16*)smem;                            // [128][72]
  const int tid  = threadIdx.x;
  const int lane = tid & 63, wv = tid >> 6;
  const int col  = lane & 15, quad = lane >> 4;
  const long p0 = (long)blockIdx.x * 128;
  f32x4 acc[8][2];
  #pragma unroll
  for (int a = 0; a < 8; a++)
    #pragma unroll
    for (int b = 0; b < 2; b++){ acc[a][b][0]=0.f; acc[a][b][1]=0.f; acc[a][b][2]=0.f; acc[a][b][3]=0.f; }
  for (int kc = 0; kc < 4; kc++){
    #pragma unroll
    for (int r = 0; r < 8; r++){
      int idx = r*256 + tid;
      int m = idx >> 4, f4 = idx & 15;
      float4 v = *(const float4*)(x + (p0+m)*CI + kc*64 + f4*4);
      u32 lo = (u32)f2bf(v.x) | ((u32)f2bf(v.y) << 16);
      u32 hi = (u32)f2bf(v.z) | ((u32)f2bf(v.w) << 16);
      *(uint2*)(As + m*K1_LS + f4*4) = make_uint2(lo, hi);
    }
    __syncthreads();
    #pragma unroll
    for (int ks = 0; ks < 2; ks++){
      const int kt = kc*2 + ks;
      bf16x8 bfr[2], af[8];
      #pragma unroll
      for (int nt = 0; nt < 2; nt++)
        bfr[nt] = *(const bf16x8*)(w1s + (size_t)(((wv*2+nt)*8 + kt)*64 + lane)*8);
      #pragma unroll
      for (int mt = 0; mt < 8; mt++)
        af[mt] = *(const bf16x8*)(As + (mt*16 + col)*K1_LS + ks*32 + quad*8);
      #pragma unroll
      for (int mt = 0; mt < 8; mt++)
        #pragma unroll
        for (int nt = 0; nt < 2; nt++)
          acc[mt][nt] = __builtin_amdgcn_mfma_f32_16x16x32_bf16(af[mt], bfr[nt], acc[mt][nt], 0, 0, 0);
    }
    __syncthreads();
  }
  u16* outw = (u16*)smem;   // [128][136]
  #pragma unroll
  for (int nt = 0; nt < 2; nt++){
    int n = wv*32 + nt*16 + col;
    float a1 = A1v[n], b1v = B1v[n];
    #pragma unroll
    for (int mt = 0; mt < 8; mt++)
      #pragma unroll
      for (int reg = 0; reg < 4; reg++){
        int m = mt*16 + quad*4 + reg;
        outw[m*136 + n] = f2bf(fmaxf(acc[mt][nt][reg]*a1 + b1v, 0.f));
      }
  }
  __syncthreads();
  #pragma unroll
  for (int r = 0; r < 8; r++){
    int idx = r*256 + tid;
    int m = idx >> 4, u4 = idx & 15;
    uint4 v = *(const uint4*)(outw + m*136 + u4*8);
    *(uint4*)(h1 + (p0+m)*CM + u4*8) = v;
  }
}

// ---------------- fused: grouped 3x3 (MFMA) + BN + ReLU + conv3 + bias + residual + ReLU ----------------
// v6: TWO rows per block (896 blocks, M=112=7x16 exact, no dead rows). Possible now
// that phase B is MFMA (R3's 2-row spill was the scalar phase B's registers).
// Full LDS overlay: tile (60928) -> h2t (28672, after sync2, acc2 in regs) ->
// pre (59136, after sync4). LDS = 60928 -> 2 blocks/CU. 4 barriers/row.
#define LSH1 136   // h1 tile stride (u16), 272 B rows: 16B-aligned
__global__ __launch_bounds__(512, 2) void k23(const u16* __restrict__ h1,
    const u16* __restrict__ w2s, const float* __restrict__ A2v,
    const float* __restrict__ B2v, const u16* __restrict__ w3s,
    const float* __restrict__ b3, const float* __restrict__ x,
    float* __restrict__ out){
  __shared__ __align__(16) char smem[4*HW*LSH1*2];   // 60928 B, all phases overlay
  u16*  tile = (u16*)smem;          // [4][56][136] bf16 (phase A/B)
  char* h2t  = smem;                // [112] rows x 256 B XOR-swizzled (phase B->C)
  float* pre = (float*)smem;        // [112][132] f32 (epilogue halves)

  const int tid = threadIdx.x;
  // XCD swizzle: grid 896 = 8 * 112
  const int bid = blockIdx.x;
  const int blk = (bid & 7)*112 + (bid >> 3);
  const int y0 = (blk % 28) * 2;            // first output row in image
  const long p0 = (long)blk * 112;          // first output pixel (2 contiguous rows)

  // ---- phase A: stage h1 rows y0-1 .. y0+2 ----
  #pragma unroll
  for (int r = 0; r < 4; r++){
    const int yy = y0 + r - 1;
    const bool valid = (yy >= 0 && yy < HW);
    const uint4* src = (const uint4*)(h1 + ((long)p0 + (long)(r-1)*HW)*CM);
    for (int i = tid; i < 896; i += 512){
      uint4 v = make_uint4(0u,0u,0u,0u);
      if (valid) v = src[i];
      int px = i >> 4, ch = (i & 15)*8;
      *(uint4*)(tile + (r*HW + px)*LSH1 + ch) = v;   // 16B-aligned
    }
  }
  __syncthreads();   // sync1: tile staged

  const int lane = tid & 63, wv = tid >> 6;
  const int col  = lane & 15, quad = lane >> 4;

  // ---- phase B: grouped 3x3 via block-diagonal MFMA ----
  // wave wv owns n-tile nt2=wv (16 ch); all 7 m-tiles (112 px = 2 rows x 56).
  const int nt2 = wv;
  f32x4 acc2[7];
  #pragma unroll
  for (int a = 0; a < 7; a++){ acc2[a][0]=0.f; acc2[a][1]=0.f; acc2[a][2]=0.f; acc2[a][3]=0.f; }
  int rbase[7], xq[7];
  #pragma unroll
  for (int mt = 0; mt < 7; mt++){
    int px = mt*16 + col;               // 0..111
    int rr = (px >= HW) ? 1 : 0;
    rbase[mt] = rr; xq[mt] = px - rr*HW;
  }
  #pragma unroll
  for (int pp = 0; pp < 5; pp++){
    const int tA = 2*pp, tB = (pp < 4) ? 2*pp + 1 : 8;
    const int dy = (quad < 2) ? tA/3 : tB/3;
    const int dx = (quad < 2) ? tA%3 : tB%3;
    bf16x8 bh = *(const bf16x8*)(w2s + (size_t)((nt2*10 + pp)*64 + lane)*8);
    bf16x8 bl = *(const bf16x8*)(w2s + (size_t)((nt2*10 + 5 + pp)*64 + lane)*8);
    #pragma unroll
    for (int mt = 0; mt < 7; mt++){
      int sx = xq[mt] + dx - 1;
      u32 mk = (sx >= 0 && sx < HW) ? 0xffffffffu : 0u;
      int sxc = sx < 0 ? 0 : (sx > 55 ? 55 : sx);
      const u16* ap = tile + ((rbase[mt]+dy)*HW + sxc)*LSH1 + (quad & 1)*8 + nt2*16;
      union { bf16x8 v; u32 w[4]; } af;
      af.v = *(const bf16x8*)ap;
      af.w[0] &= mk; af.w[1] &= mk; af.w[2] &= mk; af.w[3] &= mk;
      acc2[mt] = __builtin_amdgcn_mfma_f32_16x16x32_bf16(af.v, bh, acc2[mt], 0, 0, 0);
      acc2[mt] = __builtin_amdgcn_mfma_f32_16x16x32_bf16(af.v, bl, acc2[mt], 0, 0, 0);
    }
  }
  __syncthreads();   // sync2: all tile reads done (tile region dead; acc2 in regs)

  // ---- BN + ReLU -> bf16, write h2t (overlays tile region) ----
  {
    float a2 = A2v[nt2*16 + col], b2v = B2v[nt2*16 + col];
    #pragma unroll
    for (int mt = 0; mt < 7; mt++)
      #pragma unroll
      for (int reg = 0; reg < 4; reg++){
        int m = mt*16 + quad*4 + reg;   // 0..111, all valid
        u16 hv = f2bf(fmaxf(acc2[mt][reg]*a2 + b2v, 0.f));
        *(u16*)(h2t + m*256 + (((nt2*16 + col)*2) ^ ((m & 7) << 4))) = hv;
      }
  }
  __syncthreads();   // sync3: h2t ready

  // ---- phase C: conv3 MFMA. M=112 (7 m-tiles), wave wv owns N=[wv*32, wv*32+32) ----
  f32x4 acc3[7][2];
  #pragma unroll
  for (int a = 0; a < 7; a++)
    #pragma unroll
    for (int b = 0; b < 2; b++){ acc3[a][b][0]=0.f; acc3[a][b][1]=0.f; acc3[a][b][2]=0.f; acc3[a][b][3]=0.f; }
  float bias[2];
  #pragma unroll
  for (int nt = 0; nt < 2; nt++) bias[nt] = b3[wv*32 + nt*16 + col];
  #pragma unroll
  for (int kc = 0; kc < 4; kc++){
    bf16x8 bfr[2];
    #pragma unroll
    for (int nt = 0; nt < 2; nt++)
      bfr[nt] = *(const bf16x8*)(w3s + (size_t)(((wv*2+nt)*4 + kc)*64 + lane)*8);
    #pragma unroll
    for (int mt = 0; mt < 7; mt++){
      int row = mt*16 + col;
      bf16x8 af = *(const bf16x8*)(h2t + row*256 + ((kc*64 + quad*16) ^ ((row & 7) << 4)));
      #pragma unroll
      for (int nt = 0; nt < 2; nt++)
        acc3[mt][nt] = __builtin_amdgcn_mfma_f32_16x16x32_bf16(af, bfr[nt], acc3[mt][nt], 0, 0, 0);
    }
  }
  __syncthreads();   // sync4: h2t reads done (region free for pre overlay)

  // ---- epilogue: two n-halves through pre [112][132] f32, +residual +ReLU ----
  #pragma unroll
  for (int h = 0; h < 2; h++){
    if ((wv >> 2) == h){
      #pragma unroll
      for (int mt = 0; mt < 7; mt++)
        #pragma unroll
        for (int nt = 0; nt < 2; nt++)
          #pragma unroll
          for (int reg = 0; reg < 4; reg++){
            int m = mt*16 + quad*4 + reg;
            pre[m*132 + (wv&3)*32 + nt*16 + col] = acc3[mt][nt][reg] + bias[nt];
          }
    }
    __syncthreads();   // pre half ready
    float4 xv[7];
    #pragma unroll
    for (int it = 0; it < 7; it++){
      int i = tid + it*512;          // 3584 = 112 px x 32 f4 exactly
      int m = i >> 5, f4 = i & 31;
      xv[it] = *(const float4*)(x + (p0+m)*CI + h*128 + f4*4);
    }
    #pragma unroll
    for (int it = 0; it < 7; it++){
      int i = tid + it*512;
      int m = i >> 5, f4 = i & 31;
      float4 pv = *(const float4*)(pre + m*132 + f4*4);
      float4 o;
      o.x = fmaxf(pv.x + xv[it].x, 0.f);
      o.y = fmaxf(pv.y + xv[it].y, 0.f);
      o.z = fmaxf(pv.z + xv[it].z, 0.f);
      o.w = fmaxf(pv.w + xv[it].w, 0.f);
      *(float4*)(out + (p0+m)*CI + h*128 + f4*4) = o;
    }
    if (h == 0) __syncthreads();   // pre half-0 consumed
  }
}

extern "C" void kernel_launch(void* const* d_in, const int* in_sizes, int n_in,
                              void* d_out, int out_size, void* d_ws, size_t ws_size,
                              hipStream_t stream){
  (void)in_sizes; (void)n_in; (void)out_size; (void)ws_size;
  const float* x   = (const float*)d_in[0];
  const float* w1  = (const float*)d_in[1];
  const float* b1  = (const float*)d_in[2];
  const float* g1  = (const float*)d_in[3];
  const float* be1 = (const float*)d_in[4];
  const float* m1  = (const float*)d_in[5];
  const float* v1  = (const float*)d_in[6];
  const float* w2  = (const float*)d_in[7];
  const float* b2  = (const float*)d_in[8];
  const float* g2  = (const float*)d_in[9];
  const float* be2 = (const float*)d_in[10];
  const float* m2  = (const float*)d_in[11];
  const float* v2  = (const float*)d_in[12];
  const float* w3  = (const float*)d_in[13];
  const float* b3  = (const float*)d_in[14];

  char* ws = (char*)d_ws;
  u16* h1  = (u16*)ws;                                  // 25.69 MB
  u16* w1s = (u16*)(ws + (size_t)PIX*CM*2);             // 64 KB
  u16* w3s = w1s + 32768;                               // 64 KB
  float* A1 = (float*)(w3s + 32768);
  float* B1 = A1 + 128;
  float* A2 = B1 + 128;
  float* B2 = A2 + 128;
  u16* w2s = (u16*)(B2 + 128);                          // 80 KB

  kprep<<<160, 256, 0, stream>>>(w1,b1,g1,be1,m1,v1,w2,b2,g2,be2,m2,v2,w3,
                                 w1s,w3s,w2s,A1,B1,A2,B2);
  k1<<<PIX/128, 256, 0, stream>>>(x, w1s, A1, B1, h1);
  k23<<<NB*28, 512, 0, stream>>>(h1, w2s, A2, B2, w3s, b3, x, (float*)d_out);
}

// Round 6
// 253.502 us; speedup vs baseline: 1.0217x; 1.0217x over previous
//
#include <hip/hip_runtime.h>
#include <stdint.h>

typedef unsigned short u16;
typedef unsigned int   u32;
typedef __attribute__((ext_vector_type(8))) short bf16x8;
typedef __attribute__((ext_vector_type(4))) float f32x4;

#define EPS 1e-3f
#define NB 32
#define HW 56
#define CI 256
#define CM 128
#define PIX (NB*HW*HW)   // 100352

__device__ __forceinline__ float asf(u32 i){ union{u32 u; float f;} t; t.u=i; return t.f; }
__device__ __forceinline__ u16 f2bf(float f){
  union{float f; u32 u;} t; t.f = f;
  u32 x = t.u;
  return (u16)((x + 0x7fffu + ((x>>16)&1u)) >> 16);   // RNE
}

// ---------------- prep: MFMA-fragment-swizzled bf16 weights + BN fold ----------------
// w1s: conv1 B-frags [8 t][8 kt][64 lane][8]
// w3s: conv3 B-frags [16 t][4 kc][64 lane][8]
// w2s: conv2 (grouped 3x3) block-diagonal B-frags [8 t][10 pv][64 lane][8]
//      pv 0..4 = hi bf16 of tap-pairs (0,1)(2,3)(4,5)(6,7)(8,pad); pv 5..9 = lo residual.
__global__ __launch_bounds__(256) void kprep(
    const float* __restrict__ w1, const float* __restrict__ b1, const float* __restrict__ g1,
    const float* __restrict__ be1, const float* __restrict__ m1, const float* __restrict__ v1,
    const float* __restrict__ w2, const float* __restrict__ b2, const float* __restrict__ g2,
    const float* __restrict__ be2, const float* __restrict__ m2, const float* __restrict__ v2,
    const float* __restrict__ w3,
    u16* __restrict__ w1s, u16* __restrict__ w3s, u16* __restrict__ w2s,
    float* __restrict__ A1, float* __restrict__ B1,
    float* __restrict__ A2, float* __restrict__ B2){
  int i = blockIdx.x*256 + threadIdx.x;
  if (i < 32768){
    { // w1s
      int j = i & 7, lane = (i >> 3) & 63, kt = (i >> 9) & 7, t = i >> 12;
      int col = lane & 15, quad = lane >> 4;
      int n = t*16 + col, k = kt*32 + quad*8 + j;
      w1s[i] = f2bf(w1[k*CM + n]);
    }
    { // w3s
      int j = i & 7, lane = (i >> 3) & 63, kc = (i >> 9) & 3, t = i >> 11;
      int col = lane & 15, quad = lane >> 4;
      int n = t*16 + col, k = kc*32 + quad*8 + j;
      w3s[i] = f2bf(w3[k*CI + n]);
    }
  }
  if (i < 40960){ // w2s
    int j = i & 7, lane = (i >> 3) & 63;
    int pv = (i >> 9) % 10, t = (i >> 9) / 10;
    int pp = pv % 5; bool lo = pv >= 5;
    int col = lane & 15, quad = lane >> 4;
    int klocal = quad*8 + j;
    int tap = (klocal < 16) ? 2*pp : 2*pp + 1;   // tap 9 (pp=4 second half) = invalid -> 0
    int c = klocal & 15;
    float wv = 0.f;
    if (tap <= 8 && (c >> 2) == (col >> 2))
      wv = w2[(tap*4 + (c & 3))*CM + t*16 + col];
    u16 hi = f2bf(wv);
    if (!lo) w2s[i] = hi;
    else     w2s[i] = f2bf(wv - asf((u32)hi << 16));
  }
  if (i < 128){
    float s1 = g1[i] * rsqrtf(v1[i] + EPS);
    A1[i] = s1;
    B1[i] = b1[i]*s1 + be1[i] - m1[i]*s1;
    float s2 = g2[i] * rsqrtf(v2[i] + EPS);
    A2[i] = s2;
    B2[i] = b2[i]*s2 + be2[i] - m2[i]*s2;
  }
}

// ---------------- conv1 1x1 256->128 + BN + ReLU (MFMA bf16) ----------------
// round-0 version (best measured): 256 thr, K-chunked LDS, 4 blocks/CU.
#define K1_LS 72   // A-tile row stride (u16)
__global__ __launch_bounds__(256) void k1(const float* __restrict__ x,
    const u16* __restrict__ w1s, const float* __restrict__ A1v,
    const float* __restrict__ B1v, u16* __restrict__ h1){
  __shared__ __align__(16) char smem[128*136*2];
  u16* As = (u16*)smem;                            // [128][72]
  const int tid  = threadIdx.x;
  const int lane = tid & 63, wv = tid >> 6;
  const int col  = lane & 15, quad = lane >> 4;
  const long p0 = (long)blockIdx.x * 128;
  f32x4 acc[8][2];
  #pragma unroll
  for (int a = 0; a < 8; a++)
    #pragma unroll
    for (int b = 0; b < 2; b++){ acc[a][b][0]=0.f; acc[a][b][1]=0.f; acc[a][b][2]=0.f; acc[a][b][3]=0.f; }
  for (int kc = 0; kc < 4; kc++){
    #pragma unroll
    for (int r = 0; r < 8; r++){
      int idx = r*256 + tid;
      int m = idx >> 4, f4 = idx & 15;
      float4 v = *(const float4*)(x + (p0+m)*CI + kc*64 + f4*4);
      u32 lo = (u32)f2bf(v.x) | ((u32)f2bf(v.y) << 16);
      u32 hi = (u32)f2bf(v.z) | ((u32)f2bf(v.w) << 16);
      *(uint2*)(As + m*K1_LS + f4*4) = make_uint2(lo, hi);
    }
    __syncthreads();
    #pragma unroll
    for (int ks = 0; ks < 2; ks++){
      const int kt = kc*2 + ks;
      bf16x8 bfr[2], af[8];
      #pragma unroll
      for (int nt = 0; nt < 2; nt++)
        bfr[nt] = *(const bf16x8*)(w1s + (size_t)(((wv*2+nt)*8 + kt)*64 + lane)*8);
      #pragma unroll
      for (int mt = 0; mt < 8; mt++)
        af[mt] = *(const bf16x8*)(As + (mt*16 + col)*K1_LS + ks*32 + quad*8);
      #pragma unroll
      for (int mt = 0; mt < 8; mt++)
        #pragma unroll
        for (int nt = 0; nt < 2; nt++)
          acc[mt][nt] = __builtin_amdgcn_mfma_f32_16x16x32_bf16(af[mt], bfr[nt], acc[mt][nt], 0, 0, 0);
    }
    __syncthreads();
  }
  u16* outw = (u16*)smem;   // [128][136]
  #pragma unroll
  for (int nt = 0; nt < 2; nt++){
    int n = wv*32 + nt*16 + col;
    float a1 = A1v[n], b1v = B1v[n];
    #pragma unroll
    for (int mt = 0; mt < 8; mt++)
      #pragma unroll
      for (int reg = 0; reg < 4; reg++){
        int m = mt*16 + quad*4 + reg;
        outw[m*136 + n] = f2bf(fmaxf(acc[mt][nt][reg]*a1 + b1v, 0.f));
      }
  }
  __syncthreads();
  #pragma unroll
  for (int r = 0; r < 8; r++){
    int idx = r*256 + tid;
    int m = idx >> 4, u4 = idx & 15;
    uint4 v = *(const uint4*)(outw + m*136 + u4*8);
    *(uint4*)(h1 + (p0+m)*CM + u4*8) = v;
  }
}

// ---------------- fused: grouped 3x3 (MFMA) + BN + ReLU + conv3 + bias + residual + ReLU ----------------
// v7: ONE row per block again (1792 grid — R4 beat R5's 2-row), but with full LDS
// overlay to reach 3 blocks/CU: tile 45696 B; after sync2, h2t overlays [0,16384)
// and pre lives at [16384,45952). LDS = 45952 -> 3 blocks/CU, 24 waves/CU.
// launch_bounds(512,3) caps VGPR at ~85 (phase B/C peak ~70, no spill expected).
#define LSH1 136   // h1 tile stride (u16), 272 B rows: 16B-aligned
__global__ __launch_bounds__(512, 3) void k23(const u16* __restrict__ h1,
    const u16* __restrict__ w2s, const float* __restrict__ A2v,
    const float* __restrict__ B2v, const u16* __restrict__ w3s,
    const float* __restrict__ b3, const float* __restrict__ x,
    float* __restrict__ out){
  __shared__ __align__(16) char smem[45952];   // tile 45696 | h2t 16384 + pre 29568
  u16*  tile = (u16*)smem;                     // [3][56][136] bf16 (phase A/B)
  char* h2t  = smem;                           // [64] rows x 256 B XOR-swizzled (overlay)
  float* pre = (float*)(smem + 16384);         // [56][132] f32 (epilogue halves)

  const int tid = threadIdx.x;
  // XCD swizzle: grid 1792 = 8 * 224
  const int bid = blockIdx.x;
  const int blk = (bid & 7)*224 + (bid >> 3);
  const int y0 = blk % HW;
  const long p0 = (long)blk * HW;

  // ---- phase A: stage h1 rows y0-1..y0+1 ----
  #pragma unroll
  for (int r = 0; r < 3; r++){
    const int yy = y0 + r - 1;
    const bool valid = (yy >= 0 && yy < HW);
    const uint4* src = (const uint4*)(h1 + (long)(blk - y0 + yy)*HW*CM);
    for (int i = tid; i < 896; i += 512){
      uint4 v = make_uint4(0u,0u,0u,0u);
      if (valid) v = src[i];
      int px = i >> 4, ch = (i & 15)*8;
      *(uint4*)(tile + (r*HW + px)*LSH1 + ch) = v;   // 16B-aligned
    }
  }
  __syncthreads();   // sync1: tile staged

  const int lane = tid & 63, wv = tid >> 6;
  const int col  = lane & 15, quad = lane >> 4;

  // ---- phase B: grouped 3x3 via block-diagonal MFMA ----
  // wave (mh, nq): m-tiles {2mh,2mh+1} (M=64, rows>=56 masked), n-tiles {2nq,2nq+1}.
  const int mh = wv >> 2, nq = wv & 3;
  f32x4 acc2[2][2];
  #pragma unroll
  for (int a = 0; a < 2; a++)
    #pragma unroll
    for (int b = 0; b < 2; b++){ acc2[a][b][0]=0.f; acc2[a][b][1]=0.f; acc2[a][b][2]=0.f; acc2[a][b][3]=0.f; }
  #pragma unroll
  for (int pp = 0; pp < 5; pp++){
    const int tA = 2*pp, tB = (pp < 4) ? 2*pp + 1 : 8;
    const int dy = (quad < 2) ? tA/3 : tB/3;
    const int dx = (quad < 2) ? tA%3 : tB%3;
    bf16x8 bh[2], bl[2];
    #pragma unroll
    for (int ntl = 0; ntl < 2; ntl++){
      int nt = nq*2 + ntl;
      bh[ntl] = *(const bf16x8*)(w2s + (size_t)((nt*10 + pp)*64 + lane)*8);
      bl[ntl] = *(const bf16x8*)(w2s + (size_t)((nt*10 + 5 + pp)*64 + lane)*8);
    }
    #pragma unroll
    for (int mtl = 0; mtl < 2; mtl++){
      int px = (mh*2 + mtl)*16 + col;
      int sx = px + dx - 1;
      u32 mk = (px < HW && sx >= 0 && sx < HW) ? 0xffffffffu : 0u;
      int sxc = sx < 0 ? 0 : (sx > 55 ? 55 : sx);
      const u16* abase = tile + (dy*HW + sxc)*LSH1 + (quad & 1)*8;
      #pragma unroll
      for (int ntl = 0; ntl < 2; ntl++){
        int nt = nq*2 + ntl;
        union { bf16x8 v; u32 w[4]; } af;
        af.v = *(const bf16x8*)(abase + nt*16);
        af.w[0] &= mk; af.w[1] &= mk; af.w[2] &= mk; af.w[3] &= mk;
        acc2[mtl][ntl] = __builtin_amdgcn_mfma_f32_16x16x32_bf16(af.v, bh[ntl], acc2[mtl][ntl], 0, 0, 0);
        acc2[mtl][ntl] = __builtin_amdgcn_mfma_f32_16x16x32_bf16(af.v, bl[ntl], acc2[mtl][ntl], 0, 0, 0);
      }
    }
  }
  __syncthreads();   // sync2: ALL tile reads done (tile dead; acc2 in regs) -> overlay safe

  // ---- BN + ReLU -> bf16, write h2t (overlays tile bytes [0,16384)) ----
  #pragma unroll
  for (int ntl = 0; ntl < 2; ntl++){
    int co = (nq*2 + ntl)*16 + col;
    float a2 = A2v[co], b2v = B2v[co];
    #pragma unroll
    for (int mtl = 0; mtl < 2; mtl++)
      #pragma unroll
      for (int reg = 0; reg < 4; reg++){
        int m = (mh*2 + mtl)*16 + quad*4 + reg;
        float v = acc2[mtl][ntl][reg]*a2 + b2v;
        u16 hv = (m < HW) ? f2bf(fmaxf(v, 0.f)) : (u16)0;
        *(u16*)(h2t + m*256 + ((co*2) ^ ((m & 7) << 4))) = hv;
      }
  }
  __syncthreads();   // sync3: h2t ready

  // ---- phase C: conv3 MFMA. M=64, wave wv owns N=[wv*32, wv*32+32) ----
  f32x4 acc3[4][2];
  #pragma unroll
  for (int a = 0; a < 4; a++)
    #pragma unroll
    for (int b = 0; b < 2; b++){ acc3[a][b][0]=0.f; acc3[a][b][1]=0.f; acc3[a][b][2]=0.f; acc3[a][b][3]=0.f; }
  float bias[2];
  #pragma unroll
  for (int nt = 0; nt < 2; nt++) bias[nt] = b3[wv*32 + nt*16 + col];
  #pragma unroll
  for (int kc = 0; kc < 4; kc++){
    bf16x8 bfr[2];
    #pragma unroll
    for (int nt = 0; nt < 2; nt++)
      bfr[nt] = *(const bf16x8*)(w3s + (size_t)(((wv*2+nt)*4 + kc)*64 + lane)*8);
    #pragma unroll
    for (int mt = 0; mt < 4; mt++){
      int row = mt*16 + col;
      bf16x8 af = *(const bf16x8*)(h2t + row*256 + ((kc*64 + quad*16) ^ ((row & 7) << 4)));
      #pragma unroll
      for (int nt = 0; nt < 2; nt++)
        acc3[mt][nt] = __builtin_amdgcn_mfma_f32_16x16x32_bf16(af, bfr[nt], acc3[mt][nt], 0, 0, 0);
    }
  }
  // NOTE: no barrier needed before pre writes — pre region [16384,45952) is disjoint
  // from h2t [0,16384) (other waves may still be in phase C) and tile is dead (sync2).

  // ---- epilogue: two n-halves through pre [56][132] f32, +residual +ReLU ----
  if (wv < 4){
    #pragma unroll
    for (int mt = 0; mt < 4; mt++)
      #pragma unroll
      for (int nt = 0; nt < 2; nt++)
        #pragma unroll
        for (int reg = 0; reg < 4; reg++){
          int m = mt*16 + quad*4 + reg;
          if (m < HW)
            pre[m*132 + (wv&3)*32 + nt*16 + col] = acc3[mt][nt][reg] + bias[nt];
        }
  }
  __syncthreads();   // sync4: pre half-0 ready (all waves past phase C)
  {
    float4 xv[4];
    #pragma unroll
    for (int it = 0; it < 4; it++){
      int i = tid + it*512;
      if (i < 1792){
        int m = i >> 5, f4 = i & 31;
        xv[it] = *(const float4*)(x + (p0+m)*CI + f4*4);
      }
    }
    #pragma unroll
    for (int it = 0; it < 4; it++){
      int i = tid + it*512;
      if (i < 1792){
        int m = i >> 5, f4 = i & 31;
        float4 pv = *(const float4*)(pre + m*132 + f4*4);
        float4 o;
        o.x = fmaxf(pv.x + xv[it].x, 0.f);
        o.y = fmaxf(pv.y + xv[it].y, 0.f);
        o.z = fmaxf(pv.z + xv[it].z, 0.f);
        o.w = fmaxf(pv.w + xv[it].w, 0.f);
        *(float4*)(out + (p0+m)*CI + f4*4) = o;
      }
    }
  }
  __syncthreads();   // sync5: pre half-0 consumed

  if (wv >= 4){
    #pragma unroll
    for (int mt = 0; mt < 4; mt++)
      #pragma unroll
      for (int nt = 0; nt < 2; nt++)
        #pragma unroll
        for (int reg = 0; reg < 4; reg++){
          int m = mt*16 + quad*4 + reg;
          if (m < HW)
            pre[m*132 + (wv&3)*32 + nt*16 + col] = acc3[mt][nt][reg] + bias[nt];
        }
  }
  __syncthreads();   // sync6: pre half-1 ready
  {
    float4 xv[4];
    #pragma unroll
    for (int it = 0; it < 4; it++){
      int i = tid + it*512;
      if (i < 1792){
        int m = i >> 5, f4 = i & 31;
        xv[it] = *(const float4*)(x + (p0+m)*CI + 128 + f4*4);
      }
    }
    #pragma unroll
    for (int it = 0; it < 4; it++){
      int i = tid + it*512;
      if (i < 1792){
        int m = i >> 5, f4 = i & 31;
        float4 pv = *(const float4*)(pre + m*132 + f4*4);
        float4 o;
        o.x = fmaxf(pv.x + xv[it].x, 0.f);
        o.y = fmaxf(pv.y + xv[it].y, 0.f);
        o.z = fmaxf(pv.z + xv[it].z, 0.f);
        o.w = fmaxf(pv.w + xv[it].w, 0.f);
        *(float4*)(out + (p0+m)*CI + 128 + f4*4) = o;
      }
    }
  }
}

extern "C" void kernel_launch(void* const* d_in, const int* in_sizes, int n_in,
                              void* d_out, int out_size, void* d_ws, size_t ws_size,
                              hipStream_t stream){
  (void)in_sizes; (void)n_in; (void)out_size; (void)ws_size;
  const float* x   = (const float*)d_in[0];
  const float* w1  = (const float*)d_in[1];
  const float* b1  = (const float*)d_in[2];
  const float* g1  = (const float*)d_in[3];
  const float* be1 = (const float*)d_in[4];
  const float* m1  = (const float*)d_in[5];
  const float* v1  = (const float*)d_in[6];
  const float* w2  = (const float*)d_in[7];
  const float* b2  = (const float*)d_in[8];
  const float* g2  = (const float*)d_in[9];
  const float* be2 = (const float*)d_in[10];
  const float* m2  = (const float*)d_in[11];
  const float* v2  = (const float*)d_in[12];
  const float* w3  = (const float*)d_in[13];
  const float* b3  = (const float*)d_in[14];

  char* ws = (char*)d_ws;
  u16* h1  = (u16*)ws;                                  // 25.69 MB
  u16* w1s = (u16*)(ws + (size_t)PIX*CM*2);             // 64 KB
  u16* w3s = w1s + 32768;                               // 64 KB
  float* A1 = (float*)(w3s + 32768);
  float* B1 = A1 + 128;
  float* A2 = B1 + 128;
  float* B2 = A2 + 128;
  u16* w2s = (u16*)(B2 + 128);                          // 80 KB

  kprep<<<160, 256, 0, stream>>>(w1,b1,g1,be1,m1,v1,w2,b2,g2,be2,m2,v2,w3,
                                 w1s,w3s,w2s,A1,B1,A2,B2);
  k1<<<PIX/128, 256, 0, stream>>>(x, w1s, A1, B1, h1);
  k23<<<NB*HW, 512, 0, stream>>>(h1, w2s, A2, B2, w3s, b3, x, (float*)d_out);
}

// Round 7
// 247.935 us; speedup vs baseline: 1.0446x; 1.0225x over previous
//
#include <hip/hip_runtime.h>
#include <stdint.h>

typedef unsigned short u16;
typedef unsigned int   u32;
typedef __attribute__((ext_vector_type(8))) short bf16x8;
typedef __attribute__((ext_vector_type(4))) float f32x4;

#define EPS 1e-3f
#define NB 32
#define HW 56
#define CI 256
#define CM 128
#define PIX (NB*HW*HW)   // 100352

__device__ __forceinline__ float asf(u32 i){ union{u32 u; float f;} t; t.u=i; return t.f; }
__device__ __forceinline__ u16 f2bf(float f){
  union{float f; u32 u;} t; t.f = f;
  u32 x = t.u;
  return (u16)((x + 0x7fffu + ((x>>16)&1u)) >> 16);   // RNE
}
// packed RNE f32x2 -> bf16x2 (single VALU op; same rounding as f2bf)
__device__ __forceinline__ u32 f2bf2(float lo, float hi){
  u32 r;
  asm("v_cvt_pk_bf16_f32 %0, %1, %2" : "=v"(r) : "v"(lo), "v"(hi));
  return r;
}

// ---------------- prep: MFMA-fragment-swizzled bf16 weights + BN fold ----------------
// w1s: conv1 B-frags [8 t][8 kt][64 lane][8]
// w3s: conv3 B-frags [16 t][4 kc][64 lane][8]
// w2s: conv2 (grouped 3x3) block-diagonal B-frags [8 t][10 pv][64 lane][8]
//      pv 0..4 = hi bf16 of tap-pairs (0,1)(2,3)(4,5)(6,7)(8,pad); pv 5..9 = lo residual.
__global__ __launch_bounds__(256) void kprep(
    const float* __restrict__ w1, const float* __restrict__ b1, const float* __restrict__ g1,
    const float* __restrict__ be1, const float* __restrict__ m1, const float* __restrict__ v1,
    const float* __restrict__ w2, const float* __restrict__ b2, const float* __restrict__ g2,
    const float* __restrict__ be2, const float* __restrict__ m2, const float* __restrict__ v2,
    const float* __restrict__ w3,
    u16* __restrict__ w1s, u16* __restrict__ w3s, u16* __restrict__ w2s,
    float* __restrict__ A1, float* __restrict__ B1,
    float* __restrict__ A2, float* __restrict__ B2){
  int i = blockIdx.x*256 + threadIdx.x;
  if (i < 32768){
    { // w1s
      int j = i & 7, lane = (i >> 3) & 63, kt = (i >> 9) & 7, t = i >> 12;
      int col = lane & 15, quad = lane >> 4;
      int n = t*16 + col, k = kt*32 + quad*8 + j;
      w1s[i] = f2bf(w1[k*CM + n]);
    }
    { // w3s
      int j = i & 7, lane = (i >> 3) & 63, kc = (i >> 9) & 3, t = i >> 11;
      int col = lane & 15, quad = lane >> 4;
      int n = t*16 + col, k = kc*32 + quad*8 + j;
      w3s[i] = f2bf(w3[k*CI + n]);
    }
  }
  if (i < 40960){ // w2s
    int j = i & 7, lane = (i >> 3) & 63;
    int pv = (i >> 9) % 10, t = (i >> 9) / 10;
    int pp = pv % 5; bool lo = pv >= 5;
    int col = lane & 15, quad = lane >> 4;
    int klocal = quad*8 + j;
    int tap = (klocal < 16) ? 2*pp : 2*pp + 1;   // tap 9 (pp=4 second half) = invalid -> 0
    int c = klocal & 15;
    float wv = 0.f;
    if (tap <= 8 && (c >> 2) == (col >> 2))
      wv = w2[(tap*4 + (c & 3))*CM + t*16 + col];
    u16 hi = f2bf(wv);
    if (!lo) w2s[i] = hi;
    else     w2s[i] = f2bf(wv - asf((u32)hi << 16));
  }
  if (i < 128){
    float s1 = g1[i] * rsqrtf(v1[i] + EPS);
    A1[i] = s1;
    B1[i] = b1[i]*s1 + be1[i] - m1[i]*s1;
    float s2 = g2[i] * rsqrtf(v2[i] + EPS);
    A2[i] = s2;
    B2[i] = b2[i]*s2 + be2[i] - m2[i]*s2;
  }
}

// ---------------- conv1 1x1 256->128 + BN + ReLU (MFMA bf16) ----------------
// v4: R0 structure (K-chunked LDS staging) widened to 512 thr / 8 waves so the
// per-wave acc shrinks 64->32 VGPR, paying for a 4-float4 prefetch of chunk kc+1
// issued BEFORE the MFMA phase (T14 issue-early/write-late: HBM streams under
// MFMA instead of idling). cvt_pk bf16 conversion (1 op per 2 values).
// Peak regs ~98 < 128 cap at (512,2) = 16 waves/CU (same occupancy as R0's 4x256).
#define K1_LS 72   // A-tile row stride (u16)
__global__ __launch_bounds__(512, 2) void k1(const float* __restrict__ x,
    const u16* __restrict__ w1s, const float* __restrict__ A1v,
    const float* __restrict__ B1v, u16* __restrict__ h1){
  __shared__ __align__(16) char smem[128*136*2];   // 34816 B (A-tile 18432; epilogue 34816)
  u16* As = (u16*)smem;                            // [128][72]
  const int tid  = threadIdx.x;
  const int lane = tid & 63, wv = tid >> 6;
  const int col  = lane & 15, quad = lane >> 4;
  const int mh = wv >> 2, nq = wv & 3;             // wave: m-half (4 m-tiles), n-quarter (2 n-tiles)
  const long p0 = (long)blockIdx.x * 128;

  // fixed per-thread staging coords
  const float* xp[4];
  int sm[4], sf[4];
  #pragma unroll
  for (int r = 0; r < 4; r++){
    int idx = r*512 + tid;
    sm[r] = idx >> 4; sf[r] = idx & 15;
    xp[r] = x + (p0 + sm[r])*CI + sf[r]*4;
  }
  float4 pf[4];
  #pragma unroll
  for (int r = 0; r < 4; r++) pf[r] = *(const float4*)(xp[r]);   // chunk 0 in flight

  f32x4 acc[4][2];
  #pragma unroll
  for (int a = 0; a < 4; a++)
    #pragma unroll
    for (int b = 0; b < 2; b++){ acc[a][b][0]=0.f; acc[a][b][1]=0.f; acc[a][b][2]=0.f; acc[a][b][3]=0.f; }

  for (int kc = 0; kc < 4; kc++){
    // write staged chunk to LDS (packed cvt)
    #pragma unroll
    for (int r = 0; r < 4; r++){
      u32 lo = f2bf2(pf[r].x, pf[r].y);
      u32 hi = f2bf2(pf[r].z, pf[r].w);
      *(uint2*)(As + sm[r]*K1_LS + sf[r]*4) = make_uint2(lo, hi);
    }
    __syncthreads();   // chunk kc staged
    // issue chunk kc+1 loads NOW — they fly under the MFMA phase
    if (kc < 3){
      #pragma unroll
      for (int r = 0; r < 4; r++) pf[r] = *(const float4*)(xp[r] + (kc+1)*64);
    }
    #pragma unroll
    for (int ks = 0; ks < 2; ks++){
      const int kt = kc*2 + ks;
      bf16x8 bfr[2], af[4];
      #pragma unroll
      for (int nt = 0; nt < 2; nt++)
        bfr[nt] = *(const bf16x8*)(w1s + (size_t)(((nq*2+nt)*8 + kt)*64 + lane)*8);
      #pragma unroll
      for (int mt = 0; mt < 4; mt++)
        af[mt] = *(const bf16x8*)(As + ((mh*4+mt)*16 + col)*K1_LS + ks*32 + quad*8);
      #pragma unroll
      for (int mt = 0; mt < 4; mt++)
        #pragma unroll
        for (int nt = 0; nt < 2; nt++)
          acc[mt][nt] = __builtin_amdgcn_mfma_f32_16x16x32_bf16(af[mt], bfr[nt], acc[mt][nt], 0, 0, 0);
    }
    __syncthreads();   // As reads done, safe to overwrite next iter
  }
  // epilogue: BN + ReLU -> bf16, repack via LDS, coalesced vector store
  u16* outw = (u16*)smem;   // [128][136]
  #pragma unroll
  for (int nt = 0; nt < 2; nt++){
    int n = (nq*2+nt)*16 + col;
    float a1 = A1v[n], b1v = B1v[n];
    #pragma unroll
    for (int mt = 0; mt < 4; mt++)
      #pragma unroll
      for (int reg = 0; reg < 4; reg++){
        int m = mh*64 + mt*16 + quad*4 + reg;
        outw[m*136 + n] = f2bf(fmaxf(acc[mt][nt][reg]*a1 + b1v, 0.f));
      }
  }
  __syncthreads();
  #pragma unroll
  for (int r = 0; r < 4; r++){
    int idx = r*512 + tid;
    int m = idx >> 4, u4 = idx & 15;
    uint4 v = *(const uint4*)(outw + m*136 + u4*8);
    *(uint4*)(h1 + (p0+m)*CM + u4*8) = v;
  }
}

// ---------------- fused: grouped 3x3 (MFMA) + BN + ReLU + conv3 + bias + residual + ReLU ----------------
// REVERT to R4 version (best measured ~51 us): 1 row/block, 512 thr, 2 blocks/CU,
// free register budget (VGPR ~76). R5 (2-row) = 60.0, R6 (3 blk/CU, VGPR 48) = 63.6.
#define LSH1 136   // h1 tile stride (u16), 272 B rows: 16B-aligned
__global__ __launch_bounds__(512, 2) void k23(const u16* __restrict__ h1,
    const u16* __restrict__ w2s, const float* __restrict__ A2v,
    const float* __restrict__ B2v, const u16* __restrict__ w3s,
    const float* __restrict__ b3, const float* __restrict__ x,
    float* __restrict__ out){
  __shared__ __align__(16) char smem[3*HW*LSH1*2 + 64*256];   // 45696 + 16384 = 62080
  u16*  tile = (u16*)smem;                     // [3][56][136] bf16 (phase A/B)
  char* h2t  = smem + 3*HW*LSH1*2;             // [64] rows x 256 B, XOR-swizzled
  float* pre = (float*)smem;                   // [64][132] f32 (overlay, epilogue)

  const int tid = threadIdx.x;
  // XCD swizzle: grid 1792 = 8 * 224
  const int bid = blockIdx.x;
  const int blk = (bid & 7)*224 + (bid >> 3);
  const int y0 = blk % HW;
  const long p0 = (long)blk * HW;

  // ---- phase A: stage h1 rows y0-1..y0+1 ----
  #pragma unroll
  for (int r = 0; r < 3; r++){
    const int yy = y0 + r - 1;
    const bool valid = (yy >= 0 && yy < HW);
    const uint4* src = (const uint4*)(h1 + (long)(blk - y0 + yy)*HW*CM);
    for (int i = tid; i < 896; i += 512){
      uint4 v = make_uint4(0u,0u,0u,0u);
      if (valid) v = src[i];
      int px = i >> 4, ch = (i & 15)*8;
      *(uint4*)(tile + (r*HW + px)*LSH1 + ch) = v;   // 16B-aligned (LSH1=136)
    }
  }
  __syncthreads();   // sync1: tile staged

  // ---- residual prefetch, n-half 0 ----
  float4 xr[4];
  #pragma unroll
  for (int it = 0; it < 4; it++){
    int i = tid + it*512;
    if (i < 1792){
      int m = i >> 5, f4 = i & 31;
      xr[it] = *(const float4*)(x + (p0+m)*CI + f4*4);
    }
  }

  const int lane = tid & 63, wv = tid >> 6;
  const int col  = lane & 15, quad = lane >> 4;

  // ---- phase B: grouped 3x3 via block-diagonal MFMA ----
  // wave (mh, nq): m-tiles {2mh,2mh+1} (M=64, rows>=56 masked), n-tiles {2nq,2nq+1}.
  const int mh = wv >> 2, nq = wv & 3;
  f32x4 acc2[2][2];
  #pragma unroll
  for (int a = 0; a < 2; a++)
    #pragma unroll
    for (int b = 0; b < 2; b++){ acc2[a][b][0]=0.f; acc2[a][b][1]=0.f; acc2[a][b][2]=0.f; acc2[a][b][3]=0.f; }
  #pragma unroll
  for (int pp = 0; pp < 5; pp++){
    const int tA = 2*pp, tB = (pp < 4) ? 2*pp + 1 : 8;
    const int dy = (quad < 2) ? tA/3 : tB/3;
    const int dx = (quad < 2) ? tA%3 : tB%3;
    bf16x8 bh[2], bl[2];
    #pragma unroll
    for (int ntl = 0; ntl < 2; ntl++){
      int nt = nq*2 + ntl;
      bh[ntl] = *(const bf16x8*)(w2s + (size_t)((nt*10 + pp)*64 + lane)*8);
      bl[ntl] = *(const bf16x8*)(w2s + (size_t)((nt*10 + 5 + pp)*64 + lane)*8);
    }
    #pragma unroll
    for (int mtl = 0; mtl < 2; mtl++){
      int px = (mh*2 + mtl)*16 + col;
      int sx = px + dx - 1;
      u32 mk = (px < HW && sx >= 0 && sx < HW) ? 0xffffffffu : 0u;
      int sxc = sx < 0 ? 0 : (sx > 55 ? 55 : sx);
      const u16* abase = tile + (dy*HW + sxc)*LSH1 + (quad & 1)*8;
      #pragma unroll
      for (int ntl = 0; ntl < 2; ntl++){
        int nt = nq*2 + ntl;
        union { bf16x8 v; u32 w[4]; } af;
        af.v = *(const bf16x8*)(abase + nt*16);
        af.w[0] &= mk; af.w[1] &= mk; af.w[2] &= mk; af.w[3] &= mk;
        acc2[mtl][ntl] = __builtin_amdgcn_mfma_f32_16x16x32_bf16(af.v, bh[ntl], acc2[mtl][ntl], 0, 0, 0);
        acc2[mtl][ntl] = __builtin_amdgcn_mfma_f32_16x16x32_bf16(af.v, bl[ntl], acc2[mtl][ntl], 0, 0, 0);
      }
    }
  }
  // BN + ReLU -> bf16, write h2t swizzled (rows >= 56 forced to zero)
  #pragma unroll
  for (int ntl = 0; ntl < 2; ntl++){
    int co = (nq*2 + ntl)*16 + col;
    float a2 = A2v[co], b2v = B2v[co];
    #pragma unroll
    for (int mtl = 0; mtl < 2; mtl++)
      #pragma unroll
      for (int reg = 0; reg < 4; reg++){
        int m = (mh*2 + mtl)*16 + quad*4 + reg;
        float v = acc2[mtl][ntl][reg]*a2 + b2v;
        u16 hv = (m < HW) ? f2bf(fmaxf(v, 0.f)) : (u16)0;
        *(u16*)(h2t + m*256 + ((co*2) ^ ((m & 7) << 4))) = hv;
      }
  }
  __syncthreads();   // sync2: h2t ready (also: all tile reads done)

  // ---- phase C: conv3 MFMA. M=64, wave wv owns N=[wv*32, wv*32+32) ----
  f32x4 acc3[4][2];
  #pragma unroll
  for (int a = 0; a < 4; a++)
    #pragma unroll
    for (int b = 0; b < 2; b++){ acc3[a][b][0]=0.f; acc3[a][b][1]=0.f; acc3[a][b][2]=0.f; acc3[a][b][3]=0.f; }
  float bias[2];
  #pragma unroll
  for (int nt = 0; nt < 2; nt++) bias[nt] = b3[wv*32 + nt*16 + col];
  #pragma unroll
  for (int kc = 0; kc < 4; kc++){
    bf16x8 bfr[2];
    #pragma unroll
    for (int nt = 0; nt < 2; nt++)
      bfr[nt] = *(const bf16x8*)(w3s + (size_t)(((wv*2+nt)*4 + kc)*64 + lane)*8);
    #pragma unroll
    for (int mt = 0; mt < 4; mt++){
      int row = mt*16 + col;
      bf16x8 af = *(const bf16x8*)(h2t + row*256 + ((kc*64 + quad*16) ^ ((row & 7) << 4)));
      #pragma unroll
      for (int nt = 0; nt < 2; nt++)
        acc3[mt][nt] = __builtin_amdgcn_mfma_f32_16x16x32_bf16(af, bfr[nt], acc3[mt][nt], 0, 0, 0);
    }
  }

  // ---- epilogue: two n-halves through pre (overlays tile), +residual +ReLU ----
  if (wv < 4){
    #pragma unroll
    for (int mt = 0; mt < 4; mt++)
      #pragma unroll
      for (int nt = 0; nt < 2; nt++)
        #pragma unroll
        for (int reg = 0; reg < 4; reg++){
          int m = mt*16 + quad*4 + reg;
          pre[m*132 + (wv&3)*32 + nt*16 + col] = acc3[mt][nt][reg] + bias[nt];
        }
  }
  __syncthreads();   // sync3: pre half-0 ready
  #pragma unroll
  for (int it = 0; it < 4; it++){
    int i = tid + it*512;
    if (i < 1792){
      int m = i >> 5, f4 = i & 31;
      float4 pv = *(const float4*)(pre + m*132 + f4*4);
      float4 o;
      o.x = fmaxf(pv.x + xr[it].x, 0.f);
      o.y = fmaxf(pv.y + xr[it].y, 0.f);
      o.z = fmaxf(pv.z + xr[it].z, 0.f);
      o.w = fmaxf(pv.w + xr[it].w, 0.f);
      *(float4*)(out + (p0+m)*CI + f4*4) = o;
    }
  }
  __syncthreads();   // sync4: pre half-0 consumed

  if (wv >= 4){
    #pragma unroll
    for (int mt = 0; mt < 4; mt++)
      #pragma unroll
      for (int nt = 0; nt < 2; nt++)
        #pragma unroll
        for (int reg = 0; reg < 4; reg++){
          int m = mt*16 + quad*4 + reg;
          pre[m*132 + (wv&3)*32 + nt*16 + col] = acc3[mt][nt][reg] + bias[nt];
        }
  }
  __syncthreads();   // sync5: pre half-1 ready
  #pragma unroll
  for (int it = 0; it < 4; it++){
    int i = tid + it*512;
    if (i < 1792){
      int m = i >> 5, f4 = i & 31;
      float4 xv = *(const float4*)(x + (p0+m)*CI + 128 + f4*4);
      float4 pv = *(const float4*)(pre + m*132 + f4*4);
      float4 o;
      o.x = fmaxf(pv.x + xv.x, 0.f);
      o.y = fmaxf(pv.y + xv.y, 0.f);
      o.z = fmaxf(pv.z + xv.z, 0.f);
      o.w = fmaxf(pv.w + xv.w, 0.f);
      *(float4*)(out + (p0+m)*CI + 128 + f4*4) = o;
    }
  }
}

extern "C" void kernel_launch(void* const* d_in, const int* in_sizes, int n_in,
                              void* d_out, int out_size, void* d_ws, size_t ws_size,
                              hipStream_t stream){
  (void)in_sizes; (void)n_in; (void)out_size; (void)ws_size;
  const float* x   = (const float*)d_in[0];
  const float* w1  = (const float*)d_in[1];
  const float* b1  = (const float*)d_in[2];
  const float* g1  = (const float*)d_in[3];
  const float* be1 = (const float*)d_in[4];
  const float* m1  = (const float*)d_in[5];
  const float* v1  = (const float*)d_in[6];
  const float* w2  = (const float*)d_in[7];
  const float* b2  = (const float*)d_in[8];
  const float* g2  = (const float*)d_in[9];
  const float* be2 = (const float*)d_in[10];
  const float* m2  = (const float*)d_in[11];
  const float* v2  = (const float*)d_in[12];
  const float* w3  = (const float*)d_in[13];
  const float* b3  = (const float*)d_in[14];

  char* ws = (char*)d_ws;
  u16* h1  = (u16*)ws;                                  // 25.69 MB
  u16* w1s = (u16*)(ws + (size_t)PIX*CM*2);             // 64 KB
  u16* w3s = w1s + 32768;                               // 64 KB
  float* A1 = (float*)(w3s + 32768);
  float* B1 = A1 + 128;
  float* A2 = B1 + 128;
  float* B2 = A2 + 128;
  u16* w2s = (u16*)(B2 + 128);                          // 80 KB

  kprep<<<160, 256, 0, stream>>>(w1,b1,g1,be1,m1,v1,w2,b2,g2,be2,m2,v2,w3,
                                 w1s,w3s,w2s,A1,B1,A2,B2);
  k1<<<PIX/128, 512, 0, stream>>>(x, w1s, A1, B1, h1);
  k23<<<NB*HW, 512, 0, stream>>>(h1, w2s, A2, B2, w3s, b3, x, (float*)d_out);
}